// Round 7
// baseline (308.677 us; speedup 1.0000x reference)
//
#include <hip/hip_runtime.h>
#include <math.h>

// Problem constants
#define NF 5
#define NB 8
#define NC 64
#define HW 16384
#define NK 320               // NF*NC
#define EN_FLOATS (NB*NC*8)  // per (b,c): E0..E3, N0..N3

#define WIN1 256             // k1 spatial window (floats)
#define NT  40               // k-tiles of 8 rows (320 total)

__device__ __forceinline__ float redsum64(float v){
#pragma unroll
    for (int m = 1; m < 64; m <<= 1) v += __shfl_xor(v, m, 64);
    return v;
}

// ---------------- k1: GEMM + E/N, 8-channel waves (LDS-reuse fix) ----------------
// Round-6 post-mortem: VALUBusy 53%, dur 103us. Per-tile walls: FMA 2048cy,
// LDS read 3084cy (each wave re-reads the full tile; 4ch/wave = 1 B/FMA vs
// 0.66 B/FMA balance) -> LDS-BW-bound. Fix: wave owns 8 channels -> one
// ds_read_b128 feeds 32 FMAs (0.5 B/FMA); window 256 floats -> LDS 16 KB.
//  - Grid 1024 = 8b x 64win x 2cgrp; the 2 cgrp siblings sharing an X panel
//    sit on one XCD (blk&7) -> panel fetched once from HBM, 2x from L2.
//  - 2-tile-deep reg staging (verified r6 structure), 1 barrier/tile.
//  - Weights: direct s_load from origin_w (uniform base + imm offsets).
//  - Phase B: E/N in-register from accs, shfl butterflies, lane0 atomics.
__global__ __launch_bounds__(256, 4) void k1_fused(
    const float* __restrict__ inp, const float* __restrict__ Wg,
    const float* __restrict__ bias, float* __restrict__ EN)
{
    __shared__ float S[2*8*WIN1];   // 16 KB: two 8x256 tiles

    const int tid = threadIdx.x;
    const int l    = tid & 63;
    const int wv   = __builtin_amdgcn_readfirstlane(tid >> 6);  // 0..3
    const int blk  = blockIdx.x;
    const int xcd  = blk & 7;
    const int q    = blk >> 3;               // 0..127
    const int cgrp = q & 1;
    const int unit = xcd*64 + (q >> 1);      // 0..511 = (b, win)
    const int b    = unit >> 6;
    const int s0   = (unit & 63) << 8;       // 256-float window
    const int cf   = (cgrp << 5) + (wv << 3);// first of this wave's 8 channels
    const int srow = tid >> 5;               // staging row 0..7
    const int scol = (tid & 31) << 2;        // staging col (float)

    // accumulators: channel j (0..7), s = s0 + 4l
    float4 A[8];
    {
        float4 b0 = *reinterpret_cast<const float4*>(bias + cf);
        float4 b1 = *reinterpret_cast<const float4*>(bias + cf + 4);
        A[0] = make_float4(b0.x,b0.x,b0.x,b0.x);
        A[1] = make_float4(b0.y,b0.y,b0.y,b0.y);
        A[2] = make_float4(b0.z,b0.z,b0.z,b0.z);
        A[3] = make_float4(b0.w,b0.w,b0.w,b0.w);
        A[4] = make_float4(b1.x,b1.x,b1.x,b1.x);
        A[5] = make_float4(b1.y,b1.y,b1.y,b1.y);
        A[6] = make_float4(b1.z,b1.z,b1.z,b1.z);
        A[7] = make_float4(b1.w,b1.w,b1.w,b1.w);
    }

    const float* wbase = Wg + (size_t)cf*NK;  // uniform; s_load base

#define XROW(K) (inp + ((size_t)(((K)>>6)*NB + b)*NC + ((K)&63))*HW + s0 + scol)
#define LOADSET(R0,R1, KT) { const float* _p = XROW((KT)*8 + srow); \
    R0 = *reinterpret_cast<const float4*>(_p); \
    R1 = *reinterpret_cast<const float4*>(_p + 128); }
#define WRITESET(R0,R1, BUF) { float* _d = S + (BUF)*(8*WIN1) + srow*WIN1 + scol; \
    *reinterpret_cast<float4*>(_d)       = R0; \
    *reinterpret_cast<float4*>(_d + 128) = R1; }

    float4 rA0,rA1, rB0,rB1;
    // prologue: T0->A, T1->B, write T0, refill A with T2
    LOADSET(rA0,rA1, 0)
    LOADSET(rB0,rB1, 1)
    WRITESET(rA0,rA1, 0)            // waits only A's loads (counted vmcnt)
    LOADSET(rA0,rA1, 2)
    __syncthreads();

#pragma unroll 2
    for (int kt=0; kt<NT; ++kt){
        // write T(kt+1) into Buf[(kt+1)&1]; issue T(kt+3) into freed set
        if (kt & 1){
            if (kt < NT-1) WRITESET(rA0,rA1, (kt+1)&1)
            if (kt < NT-3) LOADSET (rA0,rA1, kt+3)
        } else {
            if (kt < NT-1) WRITESET(rB0,rB1, (kt+1)&1)
            if (kt < NT-3) LOADSET (rB0,rB1, kt+3)
        }
        const float* X  = S + (kt&1)*(8*WIN1) + (l<<2);
        const float* wt = wbase + kt*8;      // uniform; imm offsets j*NK + k
#pragma unroll
        for (int k=0; k<8; ++k){
            float4 xv = *reinterpret_cast<const float4*>(X + k*WIN1);
#pragma unroll
            for (int j=0; j<8; ++j){
                float w = wt[(size_t)j*NK + k];      // s_load, uniform
                A[j].x = fmaf(w, xv.x, A[j].x);
                A[j].y = fmaf(w, xv.y, A[j].y);
                A[j].z = fmaf(w, xv.z, A[j].z);
                A[j].w = fmaf(w, xv.w, A[j].w);
            }
        }
        __syncthreads();
    }
#undef LOADSET
#undef WRITESET
#undef XROW

    // ---- phase B: E/N for this wave's 8 channels over the 256-s window ----
#pragma unroll
    for (int j=0; j<8; ++j){
        const float* p4 = inp + ((size_t)(4*NB + b)*NC + (cf+j))*HW + s0 + (l<<2);
        float4 x4 = *reinterpret_cast<const float4*>(p4);
#pragma unroll
        for (int i=0; i<4; ++i){
            const float* pi = inp + ((size_t)(i*NB + b)*NC + (cf+j))*HW + s0 + (l<<2);
            float4 xi = *reinterpret_cast<const float4*>(pi);
            float dx = x4.x - xi.x, dy = x4.y - xi.y;
            float dz = x4.z - xi.z, dw = x4.w - xi.w;
            float n = fmaf(dx,dx, fmaf(dy,dy, fmaf(dz,dz, dw*dw)));
            float e = fmaf(A[j].x,dx, fmaf(A[j].y,dy, fmaf(A[j].z,dz, A[j].w*dw)));
            e = redsum64(e); n = redsum64(n);
            if (l == 0){
                float* p = EN + ((size_t)b*NC + cf + j)*8;
                atomicAdd(p + i,     e);
                atomicAdd(p + 4 + i, n);
            }
        }
    }
}

// ---------------- k3: finalize coefs (inlined k2) + y = alpha . inp ----------------
// 1024 blocks = (b:8) x (win:128 of 128 floats); 256 thr = 8 row-groups x 32
// float4 slots. Each block owns its output window outright: 8-way row-split
// (40 rows each), LDS float4 reduce, ONE direct store -- no atomics, no
// y-zeroing dispatch. 4 blocks/CU, 16 waves/CU; per row-group the 32 lanes
// read 512 B contiguous; 40 independent loads/thread (unroll 8).
__global__ __launch_bounds__(256, 8) void k3_out(const float* __restrict__ inp,
        const float* __restrict__ EN, const float* __restrict__ out_w,
        const float* __restrict__ out_b, float* __restrict__ y)
{
    __shared__ float  Al[NK];
    __shared__ float4 P[256];
    const int tid = threadIdx.x;
    const int blk = blockIdx.x;
    const int b   = blk >> 7;            // 0..7
    const int s0  = (blk & 127) << 7;    // 128-float window
    const int sg  = tid & 31;            // float4 slot
    const int rg  = tid >> 5;            // 0..7: 40-row group

    if (tid < 64){          // inline k2: coefs for channel c = tid
        const int c = tid;
        const float* e = EN + ((size_t)b*NC + c)*8;
        float w1 = out_w[c], w2 = out_w[NC + c];
        float csum = 0.f;
#pragma unroll
        for (int i=0; i<4; ++i){
            float nc = fmaxf(sqrtf(e[4+i]), 1e-12f);
            float coef = e[i] / (nc*nc);
            Al[i*NC + c] = -w1*coef;
            csum += coef;
        }
        Al[4*NC + c] = w1*csum + w2;
    }
    __syncthreads();

    float4 acc = make_float4(0.f,0.f,0.f,0.f);
    const int rbase = rg*40;
#pragma unroll 8
    for (int j=0; j<40; ++j){
        int r = rbase + j;
        const float* p = inp + ((size_t)((r>>6)*NB + b)*NC + (r&63))*HW + s0 + (sg<<2);
        float  w  = Al[r];                                   // half-wave-uniform broadcast
        float4 xv = *reinterpret_cast<const float4*>(p);
        acc.x = fmaf(w, xv.x, acc.x); acc.y = fmaf(w, xv.y, acc.y);
        acc.z = fmaf(w, xv.z, acc.z); acc.w = fmaf(w, xv.w, acc.w);
    }
    P[tid] = acc;
    __syncthreads();
    if (tid < 32){
        float4 r0 = P[tid];
        float vx = r0.x, vy = r0.y, vz = r0.z, vw = r0.w;
#pragma unroll
        for (int g=1; g<8; ++g){
            float4 q = P[tid + (g<<5)];
            vx += q.x; vy += q.y; vz += q.z; vw += q.w;
        }
        float bb = out_b[0];
        float4 o = make_float4(vx+bb, vy+bb, vz+bb, vw+bb);
        *reinterpret_cast<float4*>(y + (size_t)b*HW + s0 + (tid<<2)) = o;
    }
}

extern "C" void kernel_launch(void* const* d_in, const int* in_sizes, int n_in,
                              void* d_out, int out_size, void* d_ws, size_t ws_size,
                              hipStream_t stream)
{
    const float* inp      = (const float*)d_in[0];
    const float* origin_w = (const float*)d_in[1];
    const float* origin_b = (const float*)d_in[2];
    const float* out_w    = (const float*)d_in[3];
    const float* out_b    = (const float*)d_in[4];
    float* y  = (float*)d_out;
    float* EN = (float*)d_ws;            // 4096 floats

    hipMemsetAsync(EN, 0, EN_FLOATS*sizeof(float), stream);
    k1_fused<<<1024, 256, 0, stream>>>(inp, origin_w, origin_b, EN);
    k3_out  <<<1024, 256, 0, stream>>>(inp, EN, out_w, out_b, y);
}